// Round 14
// baseline (97.772 us; speedup 1.0000x reference)
//
#include <hip/hip_runtime.h>
#include <hip/hip_bf16.h>
#include <stdint.h>

#define EPSF 1e-5f

typedef short    short4v __attribute__((ext_vector_type(4)));
typedef short    short8v __attribute__((ext_vector_type(8)));
typedef float    f32x16  __attribute__((ext_vector_type(16)));
typedef float    f32x4v  __attribute__((ext_vector_type(4)));
typedef uint32_t u32x4   __attribute__((ext_vector_type(4)));

// dims: T=4, B=16, C=256, H*W=256, Hid=1024, E=8, TOPK=2 -> 32 slots
// x layout (T,B,C,H,W): idx = ((t*16+b)*256+c)*256 + hw ; t-stride = 1048576

static __device__ __forceinline__ short bf16bits(float f) {
    __hip_bfloat16 h = __float2bfloat16(f);
    return *reinterpret_cast<short*>(&h);
}

// unpack 8 spike bits -> 8 bf16 (0.0 / 1.0) entirely in registers
static __device__ __forceinline__ short8v unpack8(uint32_t by) {
    uint32_t lo = __umul24(by & 0xFu, 0x00204081u) & 0x01010101u;
    uint32_t hi = __umul24((by >> 4) & 0xFu, 0x00204081u) & 0x01010101u;
    union { short8v s; uint32_t u[4]; } r;
    r.u[0] = __umul24(__builtin_amdgcn_perm(0u, lo, 0x04010400u), 0x3F80u);
    r.u[1] = __umul24(__builtin_amdgcn_perm(0u, lo, 0x04030402u), 0x3F80u);
    r.u[2] = __umul24(__builtin_amdgcn_perm(0u, hi, 0x04010400u), 0x3F80u);
    r.u[3] = __umul24(__builtin_amdgcn_perm(0u, hi, 0x04030402u), 0x3F80u);
    return r.s;
}

// ---------------- prep: weight convert+tile (unit-major, 4 elem/thread), BN fold, router stage-1 --
// w1c[e][nt4][ks8]{ hi:[u4][n256][8sh] , lo: +8192 sh }   8 MiB   (u = cl>>3)
// w2t[e][nt4][ks16][u8][n64][8sh]                         4 MiB   (u = kl>>3)
__global__ void k_prep(const float* __restrict__ w1, const float* __restrict__ w2,
                       const float* __restrict__ x,
                       const float* __restrict__ b1, const float* __restrict__ g1, const float* __restrict__ be1,
                       const float* __restrict__ m1, const float* __restrict__ v1,
                       const float* __restrict__ b2, const float* __restrict__ g2, const float* __restrict__ be2,
                       const float* __restrict__ m2, const float* __restrict__ v2,
                       short* __restrict__ w1c, short* __restrict__ w2t,
                       float* __restrict__ sc1, float* __restrict__ sh1,
                       float* __restrict__ sc2, float* __restrict__ sh2,
                       float* __restrict__ xbar) {
    int blk = blockIdx.x;
    if (blk < 2048) {
        int i4 = (blk * 256 + threadIdx.x) * 4;
        {   // w1 hi/lo split, unit-major tile: 4 consecutive c share (e,nt,n,ks,u)
            f32x4v f = *(const f32x4v*)(w1 + i4);
            int e = i4 >> 18, o = (i4 >> 8) & 1023, c = i4 & 255;
            int nt = o >> 8, n = o & 255, ks = c >> 5, u = (c & 31) >> 3, j = c & 7;
            size_t base = ((size_t)((e * 4 + nt) * 8 + ks)) * 16384 + u * 2048 + n * 8 + j;
            short4v h4, l4;
            #pragma unroll
            for (int i = 0; i < 4; ++i) {
                __hip_bfloat16 h = __float2bfloat16(f[i]);
                h4[i] = *reinterpret_cast<short*>(&h);
                l4[i] = bf16bits(f[i] - __bfloat162float(h));
            }
            *(short4v*)(w1c + base) = h4;
            *(short4v*)(w1c + base + 8192) = l4;
        }
        {   // w2 bf16, unit-major tile: 4 consecutive k share (e,nt,n,ks,u)
            f32x4v f = *(const f32x4v*)(w2 + i4);
            int e = i4 >> 18, co = (i4 >> 10) & 255, k = i4 & 1023;
            int nt = co >> 6, n = co & 63, ks = k >> 6, u = (k & 63) >> 3, j = k & 7;
            size_t off = ((size_t)((e * 4 + nt) * 16 + ks)) * 4096 + u * 512 + n * 8 + j;
            short4v c4;
            #pragma unroll
            for (int i = 0; i < 4; ++i) c4[i] = bf16bits(f[i]);
            *(short4v*)(w2t + off) = c4;
        }
    } else if (blk < 2080) {
        int idx = (blk - 2048) * 256 + threadIdx.x;   // 0..8191
        {
            float s = g1[idx] / sqrtf(v1[idx] + EPSF);
            sc1[idx] = s;
            sh1[idx] = be1[idx] + s * (b1[idx] - m1[idx]);
        }
        if (idx < 2048) {
            float s = g2[idx] / sqrtf(v2[idx] + EPSF);
            sc2[idx] = s;
            sh2[idx] = be2[idx] + s * (b2[idx] - m2[idx]);
        }
    } else {
        // router stage 1: xbar[b*256+c] = mean over (T,H,W); 4 waves/block, 1 bc each
        int wid = threadIdx.x >> 6, lane = threadIdx.x & 63;
        int bc = (blk - 2080) * 4 + wid;
        const float* xp = x + (size_t)bc * 256;
        float s = 0.f;
        #pragma unroll
        for (int t = 0; t < 4; ++t)
            #pragma unroll
            for (int i = 0; i < 4; ++i)
                s += xp[(size_t)t * 1048576 + i * 64 + lane];
        #pragma unroll
        for (int off = 32; off; off >>= 1) s += __shfl_down(s, off);
        if (lane == 0) xbar[bc] = s * (1.0f / 1024.0f);
    }
}

// ---------------- router stage 2: logits -> top-2 -> expert-sorted 32 slots ----------------
__global__ void k_r2(const float* __restrict__ xbar, const float* __restrict__ rw, const float* __restrict__ rb,
                     const float* __restrict__ rg, const float* __restrict__ rbt,
                     const float* __restrict__ rm, const float* __restrict__ rv,
                     int* __restrict__ slotE, float* __restrict__ slotW, int* __restrict__ bslot) {
    __shared__ float L[16][8];
    __shared__ int   tE[32];
    __shared__ float tW[32];
    int tid = threadIdx.x; // 128
    if (tid < 128) {
        int b = tid >> 3, e = tid & 7;
        float s = 0.f;
        for (int c = 0; c < 256; ++c) s += xbar[b * 256 + c] * rw[e * 256 + c];
        s += rb[e];
        L[b][e] = rg[e] * (s - rm[e]) / sqrtf(rv[e] + EPSF) + rbt[e];
    }
    __syncthreads();
    if (tid < 16) {
        int b = tid;
        float l[8];
        #pragma unroll
        for (int e = 0; e < 8; ++e) l[e] = L[b][e];
        int i1 = 0;
        for (int e = 1; e < 8; ++e) if (l[e] > l[i1]) i1 = e;
        int i2 = (i1 == 0) ? 1 : 0;
        for (int e = 0; e < 8; ++e) { if (e == i1) continue; if (l[e] > l[i2]) i2 = e; }
        float d = l[i2] - l[i1];
        float ed = expf(d);
        tE[b * 2]     = i1; tW[b * 2]     = 1.f / (1.f + ed);
        tE[b * 2 + 1] = i2; tW[b * 2 + 1] = ed / (1.f + ed);
    }
    __syncthreads();
    if (tid == 0) {
        int pos = 0;
        for (int e = 0; e < 8; ++e)
            for (int i = 0; i < 32; ++i)
                if (tE[i] == e) {
                    slotE[pos] = e; slotW[pos] = tW[i];
                    bslot[i] = pos; ++pos;
                }
    }
}

// ---------------- LIF1: 32 routed slots, x read once (div-free) ----------------
// grid (16 b, 8 wq=ks, 4 hwq) x 64 thr.
// s1p layout: [slot][ks8][mrow8][l31(32)][mf4] u32 -> g1 A-load is ONE u32x4/phase.
// row = hw*4+t: mrow = hw>>5, mf = (hw>>3)&3, l31 = (hw&7)*4+t.
__global__ __launch_bounds__(64) void k_lif1(const float* __restrict__ x, const int* __restrict__ slotE,
                                             const int* __restrict__ bslot, uint32_t* __restrict__ s1p) {
    const int b = blockIdx.x, wq = blockIdx.y, hwq = blockIdx.z;
    const int s0 = bslot[b * 2], s1v = bslot[b * 2 + 1];
    const float ia = 1.0f / (1.5f + slotE[s0]  * (2.5f / 7.0f));
    const float ib = 1.0f / (1.5f + slotE[s1v] * (2.5f / 7.0f));
    const int lane = threadIdx.x;
    const int hw = hwq * 64 + lane;
    uint32_t wa[4] = {0, 0, 0, 0}, wb[4] = {0, 0, 0, 0};
    const float* xb = x + (size_t)b * 65536 + (size_t)wq * 8192 + hw;
    #pragma unroll
    for (int j0 = 0; j0 < 32; j0 += 8) {
        float xv[8][4];
        #pragma unroll
        for (int j = 0; j < 8; ++j)
            #pragma unroll
            for (int t = 0; t < 4; ++t)
                xv[j][t] = xb[(size_t)t * 1048576 + (size_t)(j0 + j) * 256];
        #pragma unroll
        for (int j = 0; j < 8; ++j) {
            const uint32_t m = 1u << (j0 + j);
            float v;
            v = xv[j][0] * ia;             if (v >= 1.f) { wa[0] |= m; v = 0.f; }
            v = fmaf(xv[j][1] - v, ia, v); if (v >= 1.f) { wa[1] |= m; v = 0.f; }
            v = fmaf(xv[j][2] - v, ia, v); if (v >= 1.f) { wa[2] |= m; v = 0.f; }
            v = fmaf(xv[j][3] - v, ia, v); if (v >= 1.f) { wa[3] |= m; }
            v = xv[j][0] * ib;             if (v >= 1.f) { wb[0] |= m; v = 0.f; }
            v = fmaf(xv[j][1] - v, ib, v); if (v >= 1.f) { wb[1] |= m; v = 0.f; }
            v = fmaf(xv[j][2] - v, ib, v); if (v >= 1.f) { wb[2] |= m; v = 0.f; }
            v = fmaf(xv[j][3] - v, ib, v); if (v >= 1.f) { wb[3] |= m; }
        }
    }
    const int mrow = hw >> 5, mf = (hw >> 3) & 3, h7 = hw & 7;
    uint32_t* p0 = s1p + ((size_t)(s0  * 8 + wq) * 8 + mrow) * 128 + mf;
    uint32_t* p1 = s1p + ((size_t)(s1v * 8 + wq) * 8 + mrow) * 128 + mf;
    #pragma unroll
    for (int t = 0; t < 4; ++t) {
        p0[(h7 * 4 + t) * 4] = wa[t];
        p1[(h7 * 4 + t) * 4] = wb[t];
    }
}

// ================= GEMM1: register-direct, barrier-free, UNPINNED schedule =================
// grid 512 = slot(32) x nt(4) x mr2(4); 512 thr = 8 waves (2 groups of 4), wave-tile 128 x 64.
// 8 phases of K=32 (hi+lo); A = one u32x4/phase; B reg double-buffer; div-free epilogue.
// NO sched_barrier / setprio: named-register deps enforce the pipeline, compiler schedules freely.
__global__ __launch_bounds__(512, 2) void k_g1(const uint32_t* __restrict__ s1p,
                                               const short* __restrict__ w1c,
                                               const float* __restrict__ sc1, const float* __restrict__ sh1,
                                               const int* __restrict__ slotE,
                                               uint32_t* __restrict__ s2p) {
    const int tid = threadIdx.x, bid = blockIdx.x;
    const int wg = ((bid & 7) << 6) | (bid >> 3);      // XCD swizzle (512 blocks)
    const int slot = wg & 31, nt = (wg >> 5) & 3, mr2 = wg >> 7;
    const int e = slotE[slot];
    const int lane = tid & 63, wid8 = tid >> 6;
    const int wid = wid8 & 3;                          // n-position within 4-wave group
    const int l31 = lane & 31, hi5 = lane >> 5;
    const int myrow = mr2 * 2 + (wid8 >> 2);           // each 4-wave group owns one mrow

    f32x16 acc[4][2];
    #pragma unroll
    for (int i = 0; i < 4; ++i)
        #pragma unroll
        for (int j = 0; j < 2; ++j) acc[i][j] = (f32x16)(0.f);

    const short* wbase = w1c + (size_t)((e * 4 + nt) * 8) * 16384 + hi5 * 2048 + (wid * 64 + l31) * 8;
    const uint32_t* abase = s1p + ((size_t)(slot * 8) * 8 + myrow) * 128 + l31 * 4;

    short8v b0[8], b1[8];
    u32x4 a0, a1;

#define G1_LDB(P, B) { const short* wp = wbase + (size_t)(P) * 16384; \
    B[0] = *(const short8v*)(wp);                B[1] = *(const short8v*)(wp + 256); \
    B[2] = *(const short8v*)(wp + 4096);         B[3] = *(const short8v*)(wp + 4352); \
    B[4] = *(const short8v*)(wp + 8192);         B[5] = *(const short8v*)(wp + 8448); \
    B[6] = *(const short8v*)(wp + 12288);        B[7] = *(const short8v*)(wp + 12544); }
#define G1_LDA(P, A) { A = *(const u32x4*)(abase + (size_t)(P) * 1024); }
#define G1_MM(A, B) { \
    _Pragma("unroll") for (int mf = 0; mf < 4; ++mf) \
      _Pragma("unroll") for (int ks = 0; ks < 2; ++ks) { \
        short8v af = unpack8((A[mf] >> ((ks * 2 + hi5) * 8)) & 0xffu); \
        _Pragma("unroll") for (int nf = 0; nf < 2; ++nf) { \
          acc[mf][nf] = __builtin_amdgcn_mfma_f32_32x32x16_bf16(af, B[ks * 2 + nf], acc[mf][nf], 0, 0, 0); \
          acc[mf][nf] = __builtin_amdgcn_mfma_f32_32x32x16_bf16(af, B[4 + ks * 2 + nf], acc[mf][nf], 0, 0, 0); \
        } } }

    G1_LDA(0, a0); G1_LDB(0, b0);
    G1_LDA(1, a1); G1_LDB(1, b1);
    G1_MM(a0, b0);
    G1_LDA(2, a0); G1_LDB(2, b0); G1_MM(a1, b1);
    G1_LDA(3, a1); G1_LDB(3, b1); G1_MM(a0, b0);
    G1_LDA(4, a0); G1_LDB(4, b0); G1_MM(a1, b1);
    G1_LDA(5, a1); G1_LDB(5, b1); G1_MM(a0, b0);
    G1_LDA(6, a0); G1_LDB(6, b0); G1_MM(a1, b1);
    G1_LDA(7, a1); G1_LDB(7, b1); G1_MM(a0, b0);
    G1_MM(a1, b1);

    // epilogue: BN1 + LIF2 (div-free) + ballot -> batched u32x4 global stores
    // C layout 32x32: col=l31, row = 8q + 4*hi5 + t  (reg = q*4 + t)
    const float invtau = 1.0f / (1.5f + e * (2.5f / 7.0f));
    #pragma unroll
    for (int mf = 0; mf < 4; ++mf) {
        #pragma unroll
        for (int nf = 0; nf < 2; ++nf) {
            int o = nt * 256 + wid * 64 + nf * 32 + l31;
            float sc = sc1[e * 1024 + o], sh = sh1[e * 1024 + o];
            int w = nt * 8 + wid * 2 + nf;
            #pragma unroll
            for (int q = 0; q < 4; ++q) {
                uint32_t wv[4];
                float v = 0.f;
                #pragma unroll
                for (int t = 0; t < 4; ++t) {
                    float bnv = fmaf(sc, acc[mf][nf][q * 4 + t], sh);
                    v = fmaf(bnv - v, invtau, v);
                    bool sp = (v >= 1.f);
                    unsigned long long bal = __ballot(sp);
                    if (sp) v = 0.f;
                    wv[t] = hi5 ? (uint32_t)(bal >> 32) : (uint32_t)bal;
                }
                if (l31 == 0) {
                    int row = myrow * 128 + mf * 32 + q * 8 + hi5 * 4;
                    *(u32x4*)&s2p[(size_t)(slot * 32 + w) * 1024 + row] =
                        (u32x4){wv[0], wv[1], wv[2], wv[3]};
                }
            }
        }
    }
#undef G1_LDB
#undef G1_LDA
#undef G1_MM
}

// ================= GEMM2: register-direct, both ranks fused, UNPINNED schedule =================
// grid 512 = b(16) x mt(8) x nt(4); 256 thr = 4 waves (rank2 x ms2), wave-tile 64 x 64 (mf=2,nf=2).
// 16 phases of K=64, reg double-buffer. LDS Y 33.3KB -> 2 blocks/CU.
__global__ __launch_bounds__(256, 2) void k_g2(const uint32_t* __restrict__ s2p,
                                               const short* __restrict__ w2t,
                                               const float* __restrict__ sc2, const float* __restrict__ sh2,
                                               const int* __restrict__ slotE, const float* __restrict__ slotW,
                                               const int* __restrict__ bslot,
                                               const float* __restrict__ x, float* __restrict__ out) {
    __shared__ float Y[4][32][65];   // 33.3 KB

    const int tid = threadIdx.x, bid = blockIdx.x;
    const int wg = ((bid & 7) << 6) | (bid >> 3);      // XCD swizzle (512 blocks)
    const int b = wg & 15, mt = (wg >> 4) & 7, nt = wg >> 7;
    const int lane = tid & 63, wid = tid >> 6;
    const int rank = wid >> 1, ms = wid & 1;
    const int l31 = lane & 31, hi5 = lane >> 5;

    const int slot = bslot[b * 2 + rank];
    const int e = slotE[slot];
    const float wgt = slotW[slot];

    f32x16 acc[2][2];
    #pragma unroll
    for (int i = 0; i < 2; ++i)
        #pragma unroll
        for (int j = 0; j < 2; ++j) acc[i][j] = (f32x16)(0.f);

    const short* wbase = w2t + (size_t)((e * 4 + nt) * 16) * 4096 + hi5 * 512 + l31 * 8;
    const uint32_t* abase = s2p + (size_t)slot * 32768 + (mt * 128 + ms * 64 + l31);

    short8v b0[8], b1[8];
    uint32_t a0[4], a1[4];

#define G2_LDB(P, B) { const short* wp = wbase + (size_t)(P) * 4096; \
    _Pragma("unroll") for (int ks = 0; ks < 4; ++ks) \
      _Pragma("unroll") for (int nf = 0; nf < 2; ++nf) \
        B[ks * 2 + nf] = *(const short8v*)(wp + ks * 1024 + nf * 256); }
#define G2_LDA(P, A) { _Pragma("unroll") for (int mf = 0; mf < 2; ++mf) { \
    A[mf * 2]     = abase[(2 * (P)) * 1024 + mf * 32]; \
    A[mf * 2 + 1] = abase[(2 * (P) + 1) * 1024 + mf * 32]; } }
#define G2_MM(A, B) { \
    _Pragma("unroll") for (int mf = 0; mf < 2; ++mf) \
      _Pragma("unroll") for (int ks = 0; ks < 4; ++ks) { \
        short8v af = unpack8((A[mf * 2 + (ks >> 1)] >> (((ks & 1) * 2 + hi5) * 8)) & 0xffu); \
        _Pragma("unroll") for (int nf = 0; nf < 2; ++nf) \
          acc[mf][nf] = __builtin_amdgcn_mfma_f32_32x32x16_bf16(af, B[ks * 2 + nf], acc[mf][nf], 0, 0, 0); } }

    G2_LDA(0, a0); G2_LDB(0, b0);
    G2_LDA(1, a1); G2_LDB(1, b1);
    G2_MM(a0, b0);
    G2_LDA(2, a0);  G2_LDB(2, b0);  G2_MM(a1, b1);
    G2_LDA(3, a1);  G2_LDB(3, b1);  G2_MM(a0, b0);
    G2_LDA(4, a0);  G2_LDB(4, b0);  G2_MM(a1, b1);
    G2_LDA(5, a1);  G2_LDB(5, b1);  G2_MM(a0, b0);
    G2_LDA(6, a0);  G2_LDB(6, b0);  G2_MM(a1, b1);
    G2_LDA(7, a1);  G2_LDB(7, b1);  G2_MM(a0, b0);
    G2_LDA(8, a0);  G2_LDB(8, b0);  G2_MM(a1, b1);
    G2_LDA(9, a1);  G2_LDB(9, b1);  G2_MM(a0, b0);
    G2_LDA(10, a0); G2_LDB(10, b0); G2_MM(a1, b1);
    G2_LDA(11, a1); G2_LDB(11, b1); G2_MM(a0, b0);
    G2_LDA(12, a0); G2_LDB(12, b0); G2_MM(a1, b1);
    G2_LDA(13, a1); G2_LDB(13, b1); G2_MM(a0, b0);
    G2_LDA(14, a0); G2_LDB(14, b0); G2_MM(a1, b1);
    G2_LDA(15, a1); G2_LDB(15, b1); G2_MM(a0, b0);
    G2_MM(a1, b1);

    // epilogue: rank1 writes wgt*y into Y, rank0 adds, then stream out = x + Y
    {
        #pragma unroll
        for (int nf = 0; nf < 2; ++nf) {
            int cl = nf * 32 + l31;
            int cg = nt * 64 + cl;
            float sc = sc2[e * 256 + cg], sh = sh2[e * 256 + cg];
            if (rank == 1) {
                #pragma unroll
                for (int mf = 0; mf < 2; ++mf)
                    #pragma unroll
                    for (int q = 0; q < 4; ++q) {
                        int hwl = ms * 16 + mf * 8 + q * 2 + hi5;
                        #pragma unroll
                        for (int t = 0; t < 4; ++t)
                            Y[t][hwl][cl] = wgt * fmaf(sc, acc[mf][nf][q * 4 + t], sh);
                    }
            }
        }
        __syncthreads();
        #pragma unroll
        for (int nf = 0; nf < 2; ++nf) {
            int cl = nf * 32 + l31;
            int cg = nt * 64 + cl;
            float sc = sc2[e * 256 + cg], sh = sh2[e * 256 + cg];
            if (rank == 0) {
                #pragma unroll
                for (int mf = 0; mf < 2; ++mf)
                    #pragma unroll
                    for (int q = 0; q < 4; ++q) {
                        int hwl = ms * 16 + mf * 8 + q * 2 + hi5;
                        #pragma unroll
                        for (int t = 0; t < 4; ++t)
                            Y[t][hwl][cl] += wgt * fmaf(sc, acc[mf][nf][q * 4 + t], sh);
                    }
            }
        }
        __syncthreads();
    }
    #pragma unroll
    for (int it = 0; it < 32; ++it) {
        int idx = it * 256 + tid;
        int hwl = idx & 31, t = (idx >> 5) & 3, cl = idx >> 7;
        size_t oidx = ((size_t)(t * 16 + b) * 256 + nt * 64 + cl) * 256 + mt * 32 + hwl;
        out[oidx] = x[oidx] + Y[t][hwl][cl];
    }
#undef G2_LDB
#undef G2_LDA
#undef G2_MM
}

extern "C" void kernel_launch(void* const* d_in, const int* in_sizes, int n_in,
                              void* d_out, int out_size, void* d_ws, size_t ws_size,
                              hipStream_t stream) {
    const float* x   = (const float*)d_in[0];
    const float* rw  = (const float*)d_in[1];
    const float* rb  = (const float*)d_in[2];
    const float* rg  = (const float*)d_in[3];
    const float* rbt = (const float*)d_in[4];
    const float* rm  = (const float*)d_in[5];
    const float* rv  = (const float*)d_in[6];
    const float* w1  = (const float*)d_in[7];
    const float* b1  = (const float*)d_in[8];
    const float* g1  = (const float*)d_in[9];
    const float* be1 = (const float*)d_in[10];
    const float* m1  = (const float*)d_in[11];
    const float* v1  = (const float*)d_in[12];
    const float* w2  = (const float*)d_in[13];
    const float* b2  = (const float*)d_in[14];
    const float* g2  = (const float*)d_in[15];
    const float* be2 = (const float*)d_in[16];
    const float* m2  = (const float*)d_in[17];
    const float* v2  = (const float*)d_in[18];
    float* out = (float*)d_out;

    char* ws = (char*)d_ws;
    short*    w1c   = (short*)(ws);                    // 8 MiB
    short*    w2t   = (short*)(ws + 8388608);          // 4 MiB
    float*    sc1   = (float*)(ws + 12582912);         // 32 KiB
    float*    sh1   = (float*)(ws + 12615680);         // 32 KiB
    float*    sc2   = (float*)(ws + 12648448);         // 8 KiB
    float*    sh2   = (float*)(ws + 12656640);         // 8 KiB
    float*    xbar  = (float*)(ws + 12664832);         // 16 KiB
    int*      slotE = (int*)  (ws + 12681216);         // 128 B
    float*    slotW = (float*)(ws + 12681344);         // 128 B
    int*      bslot = (int*)  (ws + 12681472);         // 128 B
    uint32_t* s1p   = (uint32_t*)(ws + 12681728);      // 1 MiB
    uint32_t* s2p   = (uint32_t*)(ws + 13730304);      // 4 MiB (total ~17.1 MiB)

    k_prep<<<3104, 256, 0, stream>>>(w1, w2, x, b1, g1, be1, m1, v1, b2, g2, be2, m2, v2,
                                     w1c, w2t, sc1, sh1, sc2, sh2, xbar);
    k_r2  <<<1, 128, 0, stream>>>(xbar, rw, rb, rg, rbt, rm, rv, slotE, slotW, bslot);
    k_lif1<<<dim3(16, 8, 4), 64, 0, stream>>>(x, slotE, bslot, s1p);
    k_g1  <<<512, 512, 0, stream>>>(s1p, w1c, sc1, sh1, slotE, s2p);
    k_g2  <<<512, 256, 0, stream>>>(s2p, w2t, sc2, sh2, slotE, slotW, bslot, x, out);
}

// Round 15
// 87.218 us; speedup vs baseline: 1.1210x; 1.1210x over previous
//
#include <hip/hip_runtime.h>
#include <hip/hip_bf16.h>
#include <stdint.h>

#define EPSF 1e-5f

typedef short    short4v __attribute__((ext_vector_type(4)));
typedef short    short8v __attribute__((ext_vector_type(8)));
typedef float    f32x16  __attribute__((ext_vector_type(16)));
typedef float    f32x4v  __attribute__((ext_vector_type(4)));
typedef uint32_t u32x4   __attribute__((ext_vector_type(4)));

// dims: T=4, B=16, C=256, H*W=256, Hid=1024, E=8, TOPK=2 -> 32 slots
// x layout (T,B,C,H,W): idx = ((t*16+b)*256+c)*256 + hw ; t-stride = 1048576

static __device__ __forceinline__ short bf16bits(float f) {
    __hip_bfloat16 h = __float2bfloat16(f);
    return *reinterpret_cast<short*>(&h);
}

// unpack 8 spike bits -> 8 bf16 (0.0 / 1.0) entirely in registers
static __device__ __forceinline__ short8v unpack8(uint32_t by) {
    uint32_t lo = __umul24(by & 0xFu, 0x00204081u) & 0x01010101u;
    uint32_t hi = __umul24((by >> 4) & 0xFu, 0x00204081u) & 0x01010101u;
    union { short8v s; uint32_t u[4]; } r;
    r.u[0] = __umul24(__builtin_amdgcn_perm(0u, lo, 0x04010400u), 0x3F80u);
    r.u[1] = __umul24(__builtin_amdgcn_perm(0u, lo, 0x04030402u), 0x3F80u);
    r.u[2] = __umul24(__builtin_amdgcn_perm(0u, hi, 0x04010400u), 0x3F80u);
    r.u[3] = __umul24(__builtin_amdgcn_perm(0u, hi, 0x04030402u), 0x3F80u);
    return r.s;
}

#define SCHED0() __builtin_amdgcn_sched_barrier(0)

// ---------------- prep: weight convert+tile (unit-major, 4 elem/thread), BN fold, router stage-1 --
// w1c[e][nt4][ks8]{ hi:[u4][n256][8sh] , lo: +8192 sh }   8 MiB   (u = cl>>3)
// w2t[e][nt4][ks16][u8][n64][8sh]                         4 MiB   (u = kl>>3)
__global__ void k_prep(const float* __restrict__ w1, const float* __restrict__ w2,
                       const float* __restrict__ x,
                       const float* __restrict__ b1, const float* __restrict__ g1, const float* __restrict__ be1,
                       const float* __restrict__ m1, const float* __restrict__ v1,
                       const float* __restrict__ b2, const float* __restrict__ g2, const float* __restrict__ be2,
                       const float* __restrict__ m2, const float* __restrict__ v2,
                       short* __restrict__ w1c, short* __restrict__ w2t,
                       float* __restrict__ sc1, float* __restrict__ sh1,
                       float* __restrict__ sc2, float* __restrict__ sh2,
                       float* __restrict__ xbar) {
    int blk = blockIdx.x;
    if (blk < 2048) {
        int i4 = (blk * 256 + threadIdx.x) * 4;
        {   // w1 hi/lo split, unit-major tile: 4 consecutive c share (e,nt,n,ks,u)
            f32x4v f = *(const f32x4v*)(w1 + i4);
            int e = i4 >> 18, o = (i4 >> 8) & 1023, c = i4 & 255;
            int nt = o >> 8, n = o & 255, ks = c >> 5, u = (c & 31) >> 3, j = c & 7;
            size_t base = ((size_t)((e * 4 + nt) * 8 + ks)) * 16384 + u * 2048 + n * 8 + j;
            short4v h4, l4;
            #pragma unroll
            for (int i = 0; i < 4; ++i) {
                __hip_bfloat16 h = __float2bfloat16(f[i]);
                h4[i] = *reinterpret_cast<short*>(&h);
                l4[i] = bf16bits(f[i] - __bfloat162float(h));
            }
            *(short4v*)(w1c + base) = h4;
            *(short4v*)(w1c + base + 8192) = l4;
        }
        {   // w2 bf16, unit-major tile: 4 consecutive k share (e,nt,n,ks,u)
            f32x4v f = *(const f32x4v*)(w2 + i4);
            int e = i4 >> 18, co = (i4 >> 10) & 255, k = i4 & 1023;
            int nt = co >> 6, n = co & 63, ks = k >> 6, u = (k & 63) >> 3, j = k & 7;
            size_t off = ((size_t)((e * 4 + nt) * 16 + ks)) * 4096 + u * 512 + n * 8 + j;
            short4v c4;
            #pragma unroll
            for (int i = 0; i < 4; ++i) c4[i] = bf16bits(f[i]);
            *(short4v*)(w2t + off) = c4;
        }
    } else if (blk < 2080) {
        int idx = (blk - 2048) * 256 + threadIdx.x;   // 0..8191
        {
            float s = g1[idx] / sqrtf(v1[idx] + EPSF);
            sc1[idx] = s;
            sh1[idx] = be1[idx] + s * (b1[idx] - m1[idx]);
        }
        if (idx < 2048) {
            float s = g2[idx] / sqrtf(v2[idx] + EPSF);
            sc2[idx] = s;
            sh2[idx] = be2[idx] + s * (b2[idx] - m2[idx]);
        }
    } else {
        // router stage 1: xbar[b*256+c] = mean over (T,H,W); 4 waves/block, 1 bc each
        int wid = threadIdx.x >> 6, lane = threadIdx.x & 63;
        int bc = (blk - 2080) * 4 + wid;
        const float* xp = x + (size_t)bc * 256;
        float s = 0.f;
        #pragma unroll
        for (int t = 0; t < 4; ++t)
            #pragma unroll
            for (int i = 0; i < 4; ++i)
                s += xp[(size_t)t * 1048576 + i * 64 + lane];
        #pragma unroll
        for (int off = 32; off; off >>= 1) s += __shfl_down(s, off);
        if (lane == 0) xbar[bc] = s * (1.0f / 1024.0f);
    }
}

// ---------------- router stage 2: logits -> top-2 -> expert-sorted 32 slots ----------------
__global__ void k_r2(const float* __restrict__ xbar, const float* __restrict__ rw, const float* __restrict__ rb,
                     const float* __restrict__ rg, const float* __restrict__ rbt,
                     const float* __restrict__ rm, const float* __restrict__ rv,
                     int* __restrict__ slotE, float* __restrict__ slotW, int* __restrict__ bslot) {
    __shared__ float L[16][8];
    __shared__ int   tE[32];
    __shared__ float tW[32];
    int tid = threadIdx.x; // 128
    if (tid < 128) {
        int b = tid >> 3, e = tid & 7;
        float s = 0.f;
        for (int c = 0; c < 256; ++c) s += xbar[b * 256 + c] * rw[e * 256 + c];
        s += rb[e];
        L[b][e] = rg[e] * (s - rm[e]) / sqrtf(rv[e] + EPSF) + rbt[e];
    }
    __syncthreads();
    if (tid < 16) {
        int b = tid;
        float l[8];
        #pragma unroll
        for (int e = 0; e < 8; ++e) l[e] = L[b][e];
        int i1 = 0;
        for (int e = 1; e < 8; ++e) if (l[e] > l[i1]) i1 = e;
        int i2 = (i1 == 0) ? 1 : 0;
        for (int e = 0; e < 8; ++e) { if (e == i1) continue; if (l[e] > l[i2]) i2 = e; }
        float d = l[i2] - l[i1];
        float ed = expf(d);
        tE[b * 2]     = i1; tW[b * 2]     = 1.f / (1.f + ed);
        tE[b * 2 + 1] = i2; tW[b * 2 + 1] = ed / (1.f + ed);
    }
    __syncthreads();
    if (tid == 0) {
        int pos = 0;
        for (int e = 0; e < 8; ++e)
            for (int i = 0; i < 32; ++i)
                if (tE[i] == e) {
                    slotE[pos] = e; slotW[pos] = tW[i];
                    bslot[i] = pos; ++pos;
                }
    }
}

// ---------------- LIF1: 32 routed slots, x read once (div-free) ----------------
// grid (16 b, 8 wq, 4 hwq) x 64 thr. s1p[slot][ks(8)][row(1024)] u32, row = hw*4+t.
__global__ __launch_bounds__(64) void k_lif1(const float* __restrict__ x, const int* __restrict__ slotE,
                                             const int* __restrict__ bslot, uint32_t* __restrict__ s1p) {
    const int b = blockIdx.x, wq = blockIdx.y, hwq = blockIdx.z;
    const int s0 = bslot[b * 2], s1v = bslot[b * 2 + 1];
    const float ia = 1.0f / (1.5f + slotE[s0]  * (2.5f / 7.0f));
    const float ib = 1.0f / (1.5f + slotE[s1v] * (2.5f / 7.0f));
    const int lane = threadIdx.x;
    const int hw = hwq * 64 + lane;
    uint32_t wa[4] = {0, 0, 0, 0}, wb[4] = {0, 0, 0, 0};
    const float* xb = x + (size_t)b * 65536 + (size_t)wq * 8192 + hw;
    #pragma unroll
    for (int j0 = 0; j0 < 32; j0 += 8) {
        float xv[8][4];
        #pragma unroll
        for (int j = 0; j < 8; ++j)
            #pragma unroll
            for (int t = 0; t < 4; ++t)
                xv[j][t] = xb[(size_t)t * 1048576 + (size_t)(j0 + j) * 256];
        #pragma unroll
        for (int j = 0; j < 8; ++j) {
            const uint32_t m = 1u << (j0 + j);
            float v;
            v = xv[j][0] * ia;             if (v >= 1.f) { wa[0] |= m; v = 0.f; }
            v = fmaf(xv[j][1] - v, ia, v); if (v >= 1.f) { wa[1] |= m; v = 0.f; }
            v = fmaf(xv[j][2] - v, ia, v); if (v >= 1.f) { wa[2] |= m; v = 0.f; }
            v = fmaf(xv[j][3] - v, ia, v); if (v >= 1.f) { wa[3] |= m; }
            v = xv[j][0] * ib;             if (v >= 1.f) { wb[0] |= m; v = 0.f; }
            v = fmaf(xv[j][1] - v, ib, v); if (v >= 1.f) { wb[1] |= m; v = 0.f; }
            v = fmaf(xv[j][2] - v, ib, v); if (v >= 1.f) { wb[2] |= m; v = 0.f; }
            v = fmaf(xv[j][3] - v, ib, v); if (v >= 1.f) { wb[3] |= m; }
        }
    }
    *(u32x4*)(s1p + ((size_t)s0  * 8 + wq) * 1024 + hw * 4) = (u32x4){wa[0], wa[1], wa[2], wa[3]};
    *(u32x4*)(s1p + ((size_t)s1v * 8 + wq) * 1024 + hw * 4) = (u32x4){wb[0], wb[1], wb[2], wb[3]};
}

// ================= GEMM1: register-direct, barrier-free. spikes x w1(hi/lo) + BN1 + LIF2 -> s2p ====
// grid 1024 = slot(32) x mrow(8) x nt(4); 256 thr = 4 waves, wave-tile 128 x 64.
// 8 phases of K=32 (hi+lo), B direct from L2, reg double-buffer. Epilogue: div-free LIF2 + vec stores.
__global__ __launch_bounds__(256, 2) void k_g1(const uint32_t* __restrict__ s1p,
                                               const short* __restrict__ w1c,
                                               const float* __restrict__ sc1, const float* __restrict__ sh1,
                                               const int* __restrict__ slotE,
                                               uint32_t* __restrict__ s2p) {
    const int tid = threadIdx.x, bid = blockIdx.x;
    const int wg = ((bid & 7) << 7) | (bid >> 3);      // XCD swizzle
    const int slot = wg & 31, mrow = (wg >> 5) & 7, nt = wg >> 8;
    const int e = slotE[slot];
    const int lane = tid & 63, wid = tid >> 6;
    const int l31 = lane & 31, hi5 = lane >> 5;

    f32x16 acc[4][2];
    #pragma unroll
    for (int i = 0; i < 4; ++i)
        #pragma unroll
        for (int j = 0; j < 2; ++j) acc[i][j] = (f32x16)(0.f);

    const short* wbase = w1c + (size_t)((e * 4 + nt) * 8) * 16384 + hi5 * 2048 + (wid * 64 + l31) * 8;
    const uint32_t* abase = s1p + (size_t)slot * 8192 + mrow * 128 + l31;

    short8v b0[8], b1[8];
    uint32_t a0[4], a1[4];

#define G1_LDB(P, B) { const short* wp = wbase + (size_t)(P) * 16384; \
    B[0] = *(const short8v*)(wp);                B[1] = *(const short8v*)(wp + 256); \
    B[2] = *(const short8v*)(wp + 4096);         B[3] = *(const short8v*)(wp + 4352); \
    B[4] = *(const short8v*)(wp + 8192);         B[5] = *(const short8v*)(wp + 8448); \
    B[6] = *(const short8v*)(wp + 12288);        B[7] = *(const short8v*)(wp + 12544); }
#define G1_LDA(P, A) { _Pragma("unroll") for (int mf = 0; mf < 4; ++mf) A[mf] = abase[(P) * 1024 + mf * 32]; }
#define G1_MM(A, B) { \
    __builtin_amdgcn_s_setprio(1); \
    _Pragma("unroll") for (int mf = 0; mf < 4; ++mf) \
      _Pragma("unroll") for (int ks = 0; ks < 2; ++ks) { \
        short8v af = unpack8((A[mf] >> ((ks * 2 + hi5) * 8)) & 0xffu); \
        _Pragma("unroll") for (int nf = 0; nf < 2; ++nf) { \
          acc[mf][nf] = __builtin_amdgcn_mfma_f32_32x32x16_bf16(af, B[ks * 2 + nf], acc[mf][nf], 0, 0, 0); \
          acc[mf][nf] = __builtin_amdgcn_mfma_f32_32x32x16_bf16(af, B[4 + ks * 2 + nf], acc[mf][nf], 0, 0, 0); \
        } } \
    __builtin_amdgcn_s_setprio(0); }

    G1_LDA(0, a0); G1_LDB(0, b0);
    G1_LDA(1, a1); G1_LDB(1, b1);
    G1_MM(a0, b0); SCHED0();
    G1_LDA(2, a0); G1_LDB(2, b0); G1_MM(a1, b1); SCHED0();
    G1_LDA(3, a1); G1_LDB(3, b1); G1_MM(a0, b0); SCHED0();
    G1_LDA(4, a0); G1_LDB(4, b0); G1_MM(a1, b1); SCHED0();
    G1_LDA(5, a1); G1_LDB(5, b1); G1_MM(a0, b0); SCHED0();
    G1_LDA(6, a0); G1_LDB(6, b0); G1_MM(a1, b1); SCHED0();
    G1_LDA(7, a1); G1_LDB(7, b1); G1_MM(a0, b0); SCHED0();
    G1_MM(a1, b1);

    // epilogue: BN1 + LIF2 (div-free) + ballot -> batched u32x4 global stores
    // C layout 32x32: col=l31, row = 8q + 4*hi5 + t  (reg = q*4 + t)
    const float invtau = 1.0f / (1.5f + e * (2.5f / 7.0f));
    #pragma unroll
    for (int mf = 0; mf < 4; ++mf) {
        #pragma unroll
        for (int nf = 0; nf < 2; ++nf) {
            int o = nt * 256 + wid * 64 + nf * 32 + l31;
            float sc = sc1[e * 1024 + o], sh = sh1[e * 1024 + o];
            int w = nt * 8 + wid * 2 + nf;
            #pragma unroll
            for (int q = 0; q < 4; ++q) {
                uint32_t wv[4];
                float v = 0.f;
                #pragma unroll
                for (int t = 0; t < 4; ++t) {
                    float bnv = fmaf(sc, acc[mf][nf][q * 4 + t], sh);
                    v = fmaf(bnv - v, invtau, v);
                    bool sp = (v >= 1.f);
                    unsigned long long bal = __ballot(sp);
                    if (sp) v = 0.f;
                    wv[t] = hi5 ? (uint32_t)(bal >> 32) : (uint32_t)bal;
                }
                if (l31 == 0) {
                    int row = mrow * 128 + mf * 32 + q * 8 + hi5 * 4;
                    *(u32x4*)&s2p[(size_t)(slot * 32 + w) * 1024 + row] =
                        (u32x4){wv[0], wv[1], wv[2], wv[3]};
                }
            }
        }
    }
#undef G1_LDB
#undef G1_LDA
#undef G1_MM
}

// ================= GEMM2: register-direct, both ranks fused, + BN2 + combine =================
// grid 512 = b(16) x mt(8) x nt(4); 256 thr = 4 waves (rank2 x ms2), wave-tile 64 x 64 (mf=2,nf=2).
// 16 phases of K=64, reg double-buffer. LDS Y 33.3KB -> 2 blocks/CU.
__global__ __launch_bounds__(256, 2) void k_g2(const uint32_t* __restrict__ s2p,
                                               const short* __restrict__ w2t,
                                               const float* __restrict__ sc2, const float* __restrict__ sh2,
                                               const int* __restrict__ slotE, const float* __restrict__ slotW,
                                               const int* __restrict__ bslot,
                                               const float* __restrict__ x, float* __restrict__ out) {
    __shared__ float Y[4][32][65];   // 33.3 KB

    const int tid = threadIdx.x, bid = blockIdx.x;
    const int wg = ((bid & 7) << 6) | (bid >> 3);      // XCD swizzle (512 blocks)
    const int b = wg & 15, mt = (wg >> 4) & 7, nt = wg >> 7;
    const int lane = tid & 63, wid = tid >> 6;
    const int rank = wid >> 1, ms = wid & 1;
    const int l31 = lane & 31, hi5 = lane >> 5;

    const int slot = bslot[b * 2 + rank];
    const int e = slotE[slot];
    const float wgt = slotW[slot];

    f32x16 acc[2][2];
    #pragma unroll
    for (int i = 0; i < 2; ++i)
        #pragma unroll
        for (int j = 0; j < 2; ++j) acc[i][j] = (f32x16)(0.f);

    const short* wbase = w2t + (size_t)((e * 4 + nt) * 16) * 4096 + hi5 * 512 + l31 * 8;
    const uint32_t* abase = s2p + (size_t)slot * 32768 + (mt * 128 + ms * 64 + l31);

    short8v b0[8], b1[8];
    uint32_t a0[4], a1[4];

#define G2_LDB(P, B) { const short* wp = wbase + (size_t)(P) * 4096; \
    _Pragma("unroll") for (int ks = 0; ks < 4; ++ks) \
      _Pragma("unroll") for (int nf = 0; nf < 2; ++nf) \
        B[ks * 2 + nf] = *(const short8v*)(wp + ks * 1024 + nf * 256); }
#define G2_LDA(P, A) { _Pragma("unroll") for (int mf = 0; mf < 2; ++mf) { \
    A[mf * 2]     = abase[(2 * (P)) * 1024 + mf * 32]; \
    A[mf * 2 + 1] = abase[(2 * (P) + 1) * 1024 + mf * 32]; } }
#define G2_MM(A, B) { \
    __builtin_amdgcn_s_setprio(1); \
    _Pragma("unroll") for (int mf = 0; mf < 2; ++mf) \
      _Pragma("unroll") for (int ks = 0; ks < 4; ++ks) { \
        short8v af = unpack8((A[mf * 2 + (ks >> 1)] >> (((ks & 1) * 2 + hi5) * 8)) & 0xffu); \
        _Pragma("unroll") for (int nf = 0; nf < 2; ++nf) \
          acc[mf][nf] = __builtin_amdgcn_mfma_f32_32x32x16_bf16(af, B[ks * 2 + nf], acc[mf][nf], 0, 0, 0); } \
    __builtin_amdgcn_s_setprio(0); }

    G2_LDA(0, a0); G2_LDB(0, b0);
    G2_LDA(1, a1); G2_LDB(1, b1);
    G2_MM(a0, b0); SCHED0();
    G2_LDA(2, a0);  G2_LDB(2, b0);  G2_MM(a1, b1); SCHED0();
    G2_LDA(3, a1);  G2_LDB(3, b1);  G2_MM(a0, b0); SCHED0();
    G2_LDA(4, a0);  G2_LDB(4, b0);  G2_MM(a1, b1); SCHED0();
    G2_LDA(5, a1);  G2_LDB(5, b1);  G2_MM(a0, b0); SCHED0();
    G2_LDA(6, a0);  G2_LDB(6, b0);  G2_MM(a1, b1); SCHED0();
    G2_LDA(7, a1);  G2_LDB(7, b1);  G2_MM(a0, b0); SCHED0();
    G2_LDA(8, a0);  G2_LDB(8, b0);  G2_MM(a1, b1); SCHED0();
    G2_LDA(9, a1);  G2_LDB(9, b1);  G2_MM(a0, b0); SCHED0();
    G2_LDA(10, a0); G2_LDB(10, b0); G2_MM(a1, b1); SCHED0();
    G2_LDA(11, a1); G2_LDB(11, b1); G2_MM(a0, b0); SCHED0();
    G2_LDA(12, a0); G2_LDB(12, b0); G2_MM(a1, b1); SCHED0();
    G2_LDA(13, a1); G2_LDB(13, b1); G2_MM(a0, b0); SCHED0();
    G2_LDA(14, a0); G2_LDB(14, b0); G2_MM(a1, b1); SCHED0();
    G2_LDA(15, a1); G2_LDB(15, b1); G2_MM(a0, b0); SCHED0();
    G2_MM(a1, b1);

    // epilogue: rank1 writes wgt*y into Y, rank0 adds, then stream out = x + Y
    {
        #pragma unroll
        for (int nf = 0; nf < 2; ++nf) {
            int cl = nf * 32 + l31;
            int cg = nt * 64 + cl;
            float sc = sc2[e * 256 + cg], sh = sh2[e * 256 + cg];
            if (rank == 1) {
                #pragma unroll
                for (int mf = 0; mf < 2; ++mf)
                    #pragma unroll
                    for (int q = 0; q < 4; ++q) {
                        int hwl = ms * 16 + mf * 8 + q * 2 + hi5;
                        #pragma unroll
                        for (int t = 0; t < 4; ++t)
                            Y[t][hwl][cl] = wgt * fmaf(sc, acc[mf][nf][q * 4 + t], sh);
                    }
            }
        }
        __syncthreads();
        #pragma unroll
        for (int nf = 0; nf < 2; ++nf) {
            int cl = nf * 32 + l31;
            int cg = nt * 64 + cl;
            float sc = sc2[e * 256 + cg], sh = sh2[e * 256 + cg];
            if (rank == 0) {
                #pragma unroll
                for (int mf = 0; mf < 2; ++mf)
                    #pragma unroll
                    for (int q = 0; q < 4; ++q) {
                        int hwl = ms * 16 + mf * 8 + q * 2 + hi5;
                        #pragma unroll
                        for (int t = 0; t < 4; ++t)
                            Y[t][hwl][cl] += wgt * fmaf(sc, acc[mf][nf][q * 4 + t], sh);
                    }
            }
        }
        __syncthreads();
    }
    #pragma unroll
    for (int it = 0; it < 32; ++it) {
        int idx = it * 256 + tid;
        int hwl = idx & 31, t = (idx >> 5) & 3, cl = idx >> 7;
        size_t oidx = ((size_t)(t * 16 + b) * 256 + nt * 64 + cl) * 256 + mt * 32 + hwl;
        out[oidx] = x[oidx] + Y[t][hwl][cl];
    }
#undef G2_LDB
#undef G2_LDA
#undef G2_MM
}

extern "C" void kernel_launch(void* const* d_in, const int* in_sizes, int n_in,
                              void* d_out, int out_size, void* d_ws, size_t ws_size,
                              hipStream_t stream) {
    const float* x   = (const float*)d_in[0];
    const float* rw  = (const float*)d_in[1];
    const float* rb  = (const float*)d_in[2];
    const float* rg  = (const float*)d_in[3];
    const float* rbt = (const float*)d_in[4];
    const float* rm  = (const float*)d_in[5];
    const float* rv  = (const float*)d_in[6];
    const float* w1  = (const float*)d_in[7];
    const float* b1  = (const float*)d_in[8];
    const float* g1  = (const float*)d_in[9];
    const float* be1 = (const float*)d_in[10];
    const float* m1  = (const float*)d_in[11];
    const float* v1  = (const float*)d_in[12];
    const float* w2  = (const float*)d_in[13];
    const float* b2  = (const float*)d_in[14];
    const float* g2  = (const float*)d_in[15];
    const float* be2 = (const float*)d_in[16];
    const float* m2  = (const float*)d_in[17];
    const float* v2  = (const float*)d_in[18];
    float* out = (float*)d_out;

    char* ws = (char*)d_ws;
    short*    w1c   = (short*)(ws);                    // 8 MiB
    short*    w2t   = (short*)(ws + 8388608);          // 4 MiB
    float*    sc1   = (float*)(ws + 12582912);         // 32 KiB
    float*    sh1   = (float*)(ws + 12615680);         // 32 KiB
    float*    sc2   = (float*)(ws + 12648448);         // 8 KiB
    float*    sh2   = (float*)(ws + 12656640);         // 8 KiB
    float*    xbar  = (float*)(ws + 12664832);         // 16 KiB
    int*      slotE = (int*)  (ws + 12681216);         // 128 B
    float*    slotW = (float*)(ws + 12681344);         // 128 B
    int*      bslot = (int*)  (ws + 12681472);         // 128 B
    uint32_t* s1p   = (uint32_t*)(ws + 12681728);      // 1 MiB
    uint32_t* s2p   = (uint32_t*)(ws + 13730304);      // 4 MiB (total ~17.1 MiB)

    k_prep<<<3104, 256, 0, stream>>>(w1, w2, x, b1, g1, be1, m1, v1, b2, g2, be2, m2, v2,
                                     w1c, w2t, sc1, sh1, sc2, sh2, xbar);
    k_r2  <<<1, 128, 0, stream>>>(xbar, rw, rb, rg, rbt, rm, rv, slotE, slotW, bslot);
    k_lif1<<<dim3(16, 8, 4), 64, 0, stream>>>(x, slotE, bslot, s1p);
    k_g1  <<<1024, 256, 0, stream>>>(s1p, w1c, sc1, sh1, slotE, s2p);
    k_g2  <<<512, 256, 0, stream>>>(s2p, w2t, sc2, sh2, slotE, slotW, bslot, x, out);
}

// Round 16
// 78.089 us; speedup vs baseline: 1.2521x; 1.1169x over previous
//
#include <hip/hip_runtime.h>
#include <hip/hip_bf16.h>
#include <hip/hip_fp16.h>
#include <stdint.h>

#define EPSF 1e-5f

typedef short    short4v __attribute__((ext_vector_type(4)));
typedef short    short8v __attribute__((ext_vector_type(8)));
typedef _Float16 half8v  __attribute__((ext_vector_type(8)));
typedef float    f32x16  __attribute__((ext_vector_type(16)));
typedef float    f32x4v  __attribute__((ext_vector_type(4)));
typedef uint32_t u32x4   __attribute__((ext_vector_type(4)));

// dims: T=4, B=16, C=256, H*W=256, Hid=1024, E=8, TOPK=2 -> 32 slots
// x layout (T,B,C,H,W): idx = ((t*16+b)*256+c)*256 + hw ; t-stride = 1048576

static __device__ __forceinline__ short bf16bits(float f) {
    __hip_bfloat16 h = __float2bfloat16(f);
    return *reinterpret_cast<short*>(&h);
}
static __device__ __forceinline__ short fp16bits(float f) {
    __half h = __float2half(f);
    return *reinterpret_cast<short*>(&h);
}

// unpack 8 spike bits -> 8 bf16 (0.0 / 1.0) entirely in registers
static __device__ __forceinline__ short8v unpack8(uint32_t by) {
    uint32_t lo = __umul24(by & 0xFu, 0x00204081u) & 0x01010101u;
    uint32_t hi = __umul24((by >> 4) & 0xFu, 0x00204081u) & 0x01010101u;
    union { short8v s; uint32_t u[4]; } r;
    r.u[0] = __umul24(__builtin_amdgcn_perm(0u, lo, 0x04010400u), 0x3F80u);
    r.u[1] = __umul24(__builtin_amdgcn_perm(0u, lo, 0x04030402u), 0x3F80u);
    r.u[2] = __umul24(__builtin_amdgcn_perm(0u, hi, 0x04010400u), 0x3F80u);
    r.u[3] = __umul24(__builtin_amdgcn_perm(0u, hi, 0x04030402u), 0x3F80u);
    return r.s;
}
// unpack 8 spike bits -> 8 fp16 (0.0 / 1.0): 1.0h = 0x3C00
static __device__ __forceinline__ half8v unpack8h(uint32_t by) {
    uint32_t lo = __umul24(by & 0xFu, 0x00204081u) & 0x01010101u;
    uint32_t hi = __umul24((by >> 4) & 0xFu, 0x00204081u) & 0x01010101u;
    union { half8v s; uint32_t u[4]; } r;
    r.u[0] = __umul24(__builtin_amdgcn_perm(0u, lo, 0x04010400u), 0x3C00u);
    r.u[1] = __umul24(__builtin_amdgcn_perm(0u, lo, 0x04030402u), 0x3C00u);
    r.u[2] = __umul24(__builtin_amdgcn_perm(0u, hi, 0x04010400u), 0x3C00u);
    r.u[3] = __umul24(__builtin_amdgcn_perm(0u, hi, 0x04030402u), 0x3C00u);
    return r.s;
}

#define SCHED0() __builtin_amdgcn_sched_barrier(0)

// ---------------- prep: weight convert+tile (unit-major, 4 elem/thread), BN fold, router stage-1 --
// w1h[e][nt4][ks4(K=64)][u8][n256][8sh] fp16 single plane   4 MiB   (u = (c&63)>>3)
// w2t[e][nt4][ks16][u8][n64][8sh] bf16                      4 MiB   (u = kl>>3)
__global__ void k_prep(const float* __restrict__ w1, const float* __restrict__ w2,
                       const float* __restrict__ x,
                       const float* __restrict__ b1, const float* __restrict__ g1, const float* __restrict__ be1,
                       const float* __restrict__ m1, const float* __restrict__ v1,
                       const float* __restrict__ b2, const float* __restrict__ g2, const float* __restrict__ be2,
                       const float* __restrict__ m2, const float* __restrict__ v2,
                       short* __restrict__ w1h, short* __restrict__ w2t,
                       float* __restrict__ sc1, float* __restrict__ sh1,
                       float* __restrict__ sc2, float* __restrict__ sh2,
                       float* __restrict__ xbar) {
    int blk = blockIdx.x;
    if (blk < 2048) {
        int i4 = (blk * 256 + threadIdx.x) * 4;
        {   // w1 fp16 single plane, unit-major tile (4 consecutive c share e,nt,n,ks,u)
            f32x4v f = *(const f32x4v*)(w1 + i4);
            int e = i4 >> 18, o = (i4 >> 8) & 1023, c = i4 & 255;
            int nt = o >> 8, n = o & 255, ks = c >> 6, u = (c & 63) >> 3, j = c & 7;
            size_t base = (((size_t)((e * 4 + nt) * 4 + ks)) * 8 + u) * 2048 + n * 8 + j;
            short4v h4;
            #pragma unroll
            for (int i = 0; i < 4; ++i) h4[i] = fp16bits(f[i]);
            *(short4v*)(w1h + base) = h4;
        }
        {   // w2 bf16, unit-major tile
            f32x4v f = *(const f32x4v*)(w2 + i4);
            int e = i4 >> 18, co = (i4 >> 10) & 255, k = i4 & 1023;
            int nt = co >> 6, n = co & 63, ks = k >> 6, u = (k & 63) >> 3, j = k & 7;
            size_t off = ((size_t)((e * 4 + nt) * 16 + ks)) * 4096 + u * 512 + n * 8 + j;
            short4v c4;
            #pragma unroll
            for (int i = 0; i < 4; ++i) c4[i] = bf16bits(f[i]);
            *(short4v*)(w2t + off) = c4;
        }
    } else if (blk < 2080) {
        int idx = (blk - 2048) * 256 + threadIdx.x;   // 0..8191
        {
            float s = g1[idx] / sqrtf(v1[idx] + EPSF);
            sc1[idx] = s;
            sh1[idx] = be1[idx] + s * (b1[idx] - m1[idx]);
        }
        if (idx < 2048) {
            float s = g2[idx] / sqrtf(v2[idx] + EPSF);
            sc2[idx] = s;
            sh2[idx] = be2[idx] + s * (b2[idx] - m2[idx]);
        }
    } else {
        // router stage 1: xbar[b*256+c] = mean over (T,H,W); 4 waves/block, 1 bc each
        int wid = threadIdx.x >> 6, lane = threadIdx.x & 63;
        int bc = (blk - 2080) * 4 + wid;
        const float* xp = x + (size_t)bc * 256;
        float s = 0.f;
        #pragma unroll
        for (int t = 0; t < 4; ++t)
            #pragma unroll
            for (int i = 0; i < 4; ++i)
                s += xp[(size_t)t * 1048576 + i * 64 + lane];
        #pragma unroll
        for (int off = 32; off; off >>= 1) s += __shfl_down(s, off);
        if (lane == 0) xbar[bc] = s * (1.0f / 1024.0f);
    }
}

// ---------------- router stage 2: logits -> top-2 -> expert-sorted 32 slots ----------------
__global__ void k_r2(const float* __restrict__ xbar, const float* __restrict__ rw, const float* __restrict__ rb,
                     const float* __restrict__ rg, const float* __restrict__ rbt,
                     const float* __restrict__ rm, const float* __restrict__ rv,
                     int* __restrict__ slotE, float* __restrict__ slotW, int* __restrict__ bslot) {
    __shared__ float L[16][8];
    __shared__ int   tE[32];
    __shared__ float tW[32];
    int tid = threadIdx.x; // 128
    if (tid < 128) {
        int b = tid >> 3, e = tid & 7;
        float s = 0.f;
        for (int c = 0; c < 256; ++c) s += xbar[b * 256 + c] * rw[e * 256 + c];
        s += rb[e];
        L[b][e] = rg[e] * (s - rm[e]) / sqrtf(rv[e] + EPSF) + rbt[e];
    }
    __syncthreads();
    if (tid < 16) {
        int b = tid;
        float l[8];
        #pragma unroll
        for (int e = 0; e < 8; ++e) l[e] = L[b][e];
        int i1 = 0;
        for (int e = 1; e < 8; ++e) if (l[e] > l[i1]) i1 = e;
        int i2 = (i1 == 0) ? 1 : 0;
        for (int e = 0; e < 8; ++e) { if (e == i1) continue; if (l[e] > l[i2]) i2 = e; }
        float d = l[i2] - l[i1];
        float ed = expf(d);
        tE[b * 2]     = i1; tW[b * 2]     = 1.f / (1.f + ed);
        tE[b * 2 + 1] = i2; tW[b * 2 + 1] = ed / (1.f + ed);
    }
    __syncthreads();
    if (tid == 0) {
        int pos = 0;
        for (int e = 0; e < 8; ++e)
            for (int i = 0; i < 32; ++i)
                if (tE[i] == e) {
                    slotE[pos] = e; slotW[pos] = tW[i];
                    bslot[i] = pos; ++pos;
                }
    }
}

// ---------------- LIF1: 32 routed slots, x read once (div-free) ----------------
// grid (16 b, 8 wq, 4 hwq) x 64 thr. s1p[slot][ks32(8)][row(1024)] u32, row = hw*4+t.
__global__ __launch_bounds__(64) void k_lif1(const float* __restrict__ x, const int* __restrict__ slotE,
                                             const int* __restrict__ bslot, uint32_t* __restrict__ s1p) {
    const int b = blockIdx.x, wq = blockIdx.y, hwq = blockIdx.z;
    const int s0 = bslot[b * 2], s1v = bslot[b * 2 + 1];
    const float ia = 1.0f / (1.5f + slotE[s0]  * (2.5f / 7.0f));
    const float ib = 1.0f / (1.5f + slotE[s1v] * (2.5f / 7.0f));
    const int lane = threadIdx.x;
    const int hw = hwq * 64 + lane;
    uint32_t wa[4] = {0, 0, 0, 0}, wb[4] = {0, 0, 0, 0};
    const float* xb = x + (size_t)b * 65536 + (size_t)wq * 8192 + hw;
    #pragma unroll
    for (int j0 = 0; j0 < 32; j0 += 8) {
        float xv[8][4];
        #pragma unroll
        for (int j = 0; j < 8; ++j)
            #pragma unroll
            for (int t = 0; t < 4; ++t)
                xv[j][t] = xb[(size_t)t * 1048576 + (size_t)(j0 + j) * 256];
        #pragma unroll
        for (int j = 0; j < 8; ++j) {
            const uint32_t m = 1u << (j0 + j);
            float v;
            v = xv[j][0] * ia;             if (v >= 1.f) { wa[0] |= m; v = 0.f; }
            v = fmaf(xv[j][1] - v, ia, v); if (v >= 1.f) { wa[1] |= m; v = 0.f; }
            v = fmaf(xv[j][2] - v, ia, v); if (v >= 1.f) { wa[2] |= m; v = 0.f; }
            v = fmaf(xv[j][3] - v, ia, v); if (v >= 1.f) { wa[3] |= m; }
            v = xv[j][0] * ib;             if (v >= 1.f) { wb[0] |= m; v = 0.f; }
            v = fmaf(xv[j][1] - v, ib, v); if (v >= 1.f) { wb[1] |= m; v = 0.f; }
            v = fmaf(xv[j][2] - v, ib, v); if (v >= 1.f) { wb[2] |= m; v = 0.f; }
            v = fmaf(xv[j][3] - v, ib, v); if (v >= 1.f) { wb[3] |= m; }
        }
    }
    *(u32x4*)(s1p + ((size_t)s0  * 8 + wq) * 1024 + hw * 4) = (u32x4){wa[0], wa[1], wa[2], wa[3]};
    *(u32x4*)(s1p + ((size_t)s1v * 8 + wq) * 1024 + hw * 4) = (u32x4){wb[0], wb[1], wb[2], wb[3]};
}

// ================= GEMM1: fp16 single-plane, register-direct, 4 phases of K=64 =================
// grid 1024 = slot(32) x mrow(8) x nt(4); 256 thr = 4 waves, wave-tile 128 x 64.
// Per phase: 8 B-frag loads + 8 A-dwords + 16 unpacks + 32 MFMA (f16). Div-free epilogue.
__global__ __launch_bounds__(256, 2) void k_g1(const uint32_t* __restrict__ s1p,
                                               const short* __restrict__ w1h,
                                               const float* __restrict__ sc1, const float* __restrict__ sh1,
                                               const int* __restrict__ slotE,
                                               uint32_t* __restrict__ s2p) {
    const int tid = threadIdx.x, bid = blockIdx.x;
    const int wg = ((bid & 7) << 7) | (bid >> 3);      // XCD swizzle
    const int slot = wg & 31, mrow = (wg >> 5) & 7, nt = wg >> 8;
    const int e = slotE[slot];
    const int lane = tid & 63, wid = tid >> 6;
    const int l31 = lane & 31, hi5 = lane >> 5;

    f32x16 acc[4][2];
    #pragma unroll
    for (int i = 0; i < 4; ++i)
        #pragma unroll
        for (int j = 0; j < 2; ++j) acc[i][j] = (f32x16)(0.f);

    const short* wbase = w1h + (size_t)((e * 4 + nt) * 4) * 16384 + hi5 * 2048 + (wid * 64 + l31) * 8;
    const uint32_t* abase = s1p + (size_t)slot * 8192 + mrow * 128 + l31;

    half8v b0[8], b1[8];
    uint32_t a0[8], a1[8];

#define G1_LDB(P, B) { const short* wp = wbase + (size_t)(P) * 16384; \
    _Pragma("unroll") for (int s = 0; s < 4; ++s) \
      _Pragma("unroll") for (int nf = 0; nf < 2; ++nf) \
        B[s * 2 + nf] = *(const half8v*)(wp + s * 4096 + nf * 256); }
#define G1_LDA(P, A) { _Pragma("unroll") for (int mf = 0; mf < 4; ++mf) { \
    A[mf * 2]     = abase[(2 * (P)) * 1024 + mf * 32]; \
    A[mf * 2 + 1] = abase[(2 * (P) + 1) * 1024 + mf * 32]; } }
#define G1_MM(A, B) { \
    __builtin_amdgcn_s_setprio(1); \
    _Pragma("unroll") for (int mf = 0; mf < 4; ++mf) \
      _Pragma("unroll") for (int s = 0; s < 4; ++s) { \
        half8v af = unpack8h((A[mf * 2 + (s >> 1)] >> (((s & 1) * 2 + hi5) * 8)) & 0xffu); \
        _Pragma("unroll") for (int nf = 0; nf < 2; ++nf) \
          acc[mf][nf] = __builtin_amdgcn_mfma_f32_32x32x16_f16(af, B[s * 2 + nf], acc[mf][nf], 0, 0, 0); } \
    __builtin_amdgcn_s_setprio(0); }

    G1_LDA(0, a0); G1_LDB(0, b0);
    G1_LDA(1, a1); G1_LDB(1, b1);
    G1_MM(a0, b0); SCHED0();
    G1_LDA(2, a0); G1_LDB(2, b0); G1_MM(a1, b1); SCHED0();
    G1_LDA(3, a1); G1_LDB(3, b1); G1_MM(a0, b0); SCHED0();
    G1_MM(a1, b1);

    // epilogue: BN1 + LIF2 (div-free) + ballot -> batched u32x4 global stores
    // C layout 32x32: col=l31, row = 8q + 4*hi5 + t  (reg = q*4 + t)
    const float invtau = 1.0f / (1.5f + e * (2.5f / 7.0f));
    #pragma unroll
    for (int mf = 0; mf < 4; ++mf) {
        #pragma unroll
        for (int nf = 0; nf < 2; ++nf) {
            int o = nt * 256 + wid * 64 + nf * 32 + l31;
            float sc = sc1[e * 1024 + o], sh = sh1[e * 1024 + o];
            int w = nt * 8 + wid * 2 + nf;
            #pragma unroll
            for (int q = 0; q < 4; ++q) {
                uint32_t wv[4];
                float v = 0.f;
                #pragma unroll
                for (int t = 0; t < 4; ++t) {
                    float bnv = fmaf(sc, acc[mf][nf][q * 4 + t], sh);
                    v = fmaf(bnv - v, invtau, v);
                    bool sp = (v >= 1.f);
                    unsigned long long bal = __ballot(sp);
                    if (sp) v = 0.f;
                    wv[t] = hi5 ? (uint32_t)(bal >> 32) : (uint32_t)bal;
                }
                if (l31 == 0) {
                    int row = mrow * 128 + mf * 32 + q * 8 + hi5 * 4;
                    *(u32x4*)&s2p[(size_t)(slot * 32 + w) * 1024 + row] =
                        (u32x4){wv[0], wv[1], wv[2], wv[3]};
                }
            }
        }
    }
#undef G1_LDB
#undef G1_LDA
#undef G1_MM
}

// ================= GEMM2: register-direct, both ranks fused, + BN2 + combine =================
// grid 512 = b(16) x mt(8) x nt(4); 256 thr = 4 waves (rank2 x ms2), wave-tile 64 x 64 (mf=2,nf=2).
// 16 phases of K=64, reg double-buffer. LDS Y 33.3KB -> 2 blocks/CU.
__global__ __launch_bounds__(256, 2) void k_g2(const uint32_t* __restrict__ s2p,
                                               const short* __restrict__ w2t,
                                               const float* __restrict__ sc2, const float* __restrict__ sh2,
                                               const int* __restrict__ slotE, const float* __restrict__ slotW,
                                               const int* __restrict__ bslot,
                                               const float* __restrict__ x, float* __restrict__ out) {
    __shared__ float Y[4][32][65];   // 33.3 KB

    const int tid = threadIdx.x, bid = blockIdx.x;
    const int wg = ((bid & 7) << 6) | (bid >> 3);      // XCD swizzle (512 blocks)
    const int b = wg & 15, mt = (wg >> 4) & 7, nt = wg >> 7;
    const int lane = tid & 63, wid = tid >> 6;
    const int rank = wid >> 1, ms = wid & 1;
    const int l31 = lane & 31, hi5 = lane >> 5;

    const int slot = bslot[b * 2 + rank];
    const int e = slotE[slot];
    const float wgt = slotW[slot];

    f32x16 acc[2][2];
    #pragma unroll
    for (int i = 0; i < 2; ++i)
        #pragma unroll
        for (int j = 0; j < 2; ++j) acc[i][j] = (f32x16)(0.f);

    const short* wbase = w2t + (size_t)((e * 4 + nt) * 16) * 4096 + hi5 * 512 + l31 * 8;
    const uint32_t* abase = s2p + (size_t)slot * 32768 + (mt * 128 + ms * 64 + l31);

    short8v b0[8], b1[8];
    uint32_t a0[4], a1[4];

#define G2_LDB(P, B) { const short* wp = wbase + (size_t)(P) * 4096; \
    _Pragma("unroll") for (int ks = 0; ks < 4; ++ks) \
      _Pragma("unroll") for (int nf = 0; nf < 2; ++nf) \
        B[ks * 2 + nf] = *(const short8v*)(wp + ks * 1024 + nf * 256); }
#define G2_LDA(P, A) { _Pragma("unroll") for (int mf = 0; mf < 2; ++mf) { \
    A[mf * 2]     = abase[(2 * (P)) * 1024 + mf * 32]; \
    A[mf * 2 + 1] = abase[(2 * (P) + 1) * 1024 + mf * 32]; } }
#define G2_MM(A, B) { \
    __builtin_amdgcn_s_setprio(1); \
    _Pragma("unroll") for (int mf = 0; mf < 2; ++mf) \
      _Pragma("unroll") for (int ks = 0; ks < 4; ++ks) { \
        short8v af = unpack8((A[mf * 2 + (ks >> 1)] >> (((ks & 1) * 2 + hi5) * 8)) & 0xffu); \
        _Pragma("unroll") for (int nf = 0; nf < 2; ++nf) \
          acc[mf][nf] = __builtin_amdgcn_mfma_f32_32x32x16_bf16(af, B[ks * 2 + nf], acc[mf][nf], 0, 0, 0); } \
    __builtin_amdgcn_s_setprio(0); }

    G2_LDA(0, a0); G2_LDB(0, b0);
    G2_LDA(1, a1); G2_LDB(1, b1);
    G2_MM(a0, b0); SCHED0();
    G2_LDA(2, a0);  G2_LDB(2, b0);  G2_MM(a1, b1); SCHED0();
    G2_LDA(3, a1);  G2_LDB(3, b1);  G2_MM(a0, b0); SCHED0();
    G2_LDA(4, a0);  G2_LDB(4, b0);  G2_MM(a1, b1); SCHED0();
    G2_LDA(5, a1);  G2_LDB(5, b1);  G2_MM(a0, b0); SCHED0();
    G2_LDA(6, a0);  G2_LDB(6, b0);  G2_MM(a1, b1); SCHED0();
    G2_LDA(7, a1);  G2_LDB(7, b1);  G2_MM(a0, b0); SCHED0();
    G2_LDA(8, a0);  G2_LDB(8, b0);  G2_MM(a1, b1); SCHED0();
    G2_LDA(9, a1);  G2_LDB(9, b1);  G2_MM(a0, b0); SCHED0();
    G2_LDA(10, a0); G2_LDB(10, b0); G2_MM(a1, b1); SCHED0();
    G2_LDA(11, a1); G2_LDB(11, b1); G2_MM(a0, b0); SCHED0();
    G2_LDA(12, a0); G2_LDB(12, b0); G2_MM(a1, b1); SCHED0();
    G2_LDA(13, a1); G2_LDB(13, b1); G2_MM(a0, b0); SCHED0();
    G2_LDA(14, a0); G2_LDB(14, b0); G2_MM(a1, b1); SCHED0();
    G2_LDA(15, a1); G2_LDB(15, b1); G2_MM(a0, b0); SCHED0();
    G2_MM(a1, b1);

    // epilogue: rank1 writes wgt*y into Y, rank0 adds, then stream out = x + Y
    {
        #pragma unroll
        for (int nf = 0; nf < 2; ++nf) {
            int cl = nf * 32 + l31;
            int cg = nt * 64 + cl;
            float sc = sc2[e * 256 + cg], sh = sh2[e * 256 + cg];
            if (rank == 1) {
                #pragma unroll
                for (int mf = 0; mf < 2; ++mf)
                    #pragma unroll
                    for (int q = 0; q < 4; ++q) {
                        int hwl = ms * 16 + mf * 8 + q * 2 + hi5;
                        #pragma unroll
                        for (int t = 0; t < 4; ++t)
                            Y[t][hwl][cl] = wgt * fmaf(sc, acc[mf][nf][q * 4 + t], sh);
                    }
            }
        }
        __syncthreads();
        #pragma unroll
        for (int nf = 0; nf < 2; ++nf) {
            int cl = nf * 32 + l31;
            int cg = nt * 64 + cl;
            float sc = sc2[e * 256 + cg], sh = sh2[e * 256 + cg];
            if (rank == 0) {
                #pragma unroll
                for (int mf = 0; mf < 2; ++mf)
                    #pragma unroll
                    for (int q = 0; q < 4; ++q) {
                        int hwl = ms * 16 + mf * 8 + q * 2 + hi5;
                        #pragma unroll
                        for (int t = 0; t < 4; ++t)
                            Y[t][hwl][cl] += wgt * fmaf(sc, acc[mf][nf][q * 4 + t], sh);
                    }
            }
        }
        __syncthreads();
    }
    #pragma unroll
    for (int it = 0; it < 32; ++it) {
        int idx = it * 256 + tid;
        int hwl = idx & 31, t = (idx >> 5) & 3, cl = idx >> 7;
        size_t oidx = ((size_t)(t * 16 + b) * 256 + nt * 64 + cl) * 256 + mt * 32 + hwl;
        out[oidx] = x[oidx] + Y[t][hwl][cl];
    }
#undef G2_LDB
#undef G2_LDA
#undef G2_MM
}

extern "C" void kernel_launch(void* const* d_in, const int* in_sizes, int n_in,
                              void* d_out, int out_size, void* d_ws, size_t ws_size,
                              hipStream_t stream) {
    const float* x   = (const float*)d_in[0];
    const float* rw  = (const float*)d_in[1];
    const float* rb  = (const float*)d_in[2];
    const float* rg  = (const float*)d_in[3];
    const float* rbt = (const float*)d_in[4];
    const float* rm  = (const float*)d_in[5];
    const float* rv  = (const float*)d_in[6];
    const float* w1  = (const float*)d_in[7];
    const float* b1  = (const float*)d_in[8];
    const float* g1  = (const float*)d_in[9];
    const float* be1 = (const float*)d_in[10];
    const float* m1  = (const float*)d_in[11];
    const float* v1  = (const float*)d_in[12];
    const float* w2  = (const float*)d_in[13];
    const float* b2  = (const float*)d_in[14];
    const float* g2  = (const float*)d_in[15];
    const float* be2 = (const float*)d_in[16];
    const float* m2  = (const float*)d_in[17];
    const float* v2  = (const float*)d_in[18];
    float* out = (float*)d_out;

    char* ws = (char*)d_ws;
    short*    w1h   = (short*)(ws);                    // 4 MiB (fp16 single plane)
    short*    w2t   = (short*)(ws + 4194304);          // 4 MiB
    float*    sc1   = (float*)(ws + 8388608);          // 32 KiB
    float*    sh1   = (float*)(ws + 8421376);          // 32 KiB
    float*    sc2   = (float*)(ws + 8454144);          // 8 KiB
    float*    sh2   = (float*)(ws + 8462336);          // 8 KiB
    float*    xbar  = (float*)(ws + 8470528);          // 16 KiB
    int*      slotE = (int*)  (ws + 8486912);          // 128 B
    float*    slotW = (float*)(ws + 8487040);          // 128 B
    int*      bslot = (int*)  (ws + 8487168);          // 128 B
    uint32_t* s1p   = (uint32_t*)(ws + 8487424);       // 1 MiB
    uint32_t* s2p   = (uint32_t*)(ws + 9536000);       // 4 MiB (total ~13.7 MiB)

    k_prep<<<3104, 256, 0, stream>>>(w1, w2, x, b1, g1, be1, m1, v1, b2, g2, be2, m2, v2,
                                     w1h, w2t, sc1, sh1, sc2, sh2, xbar);
    k_r2  <<<1, 128, 0, stream>>>(xbar, rw, rb, rg, rbt, rm, rv, slotE, slotW, bslot);
    k_lif1<<<dim3(16, 8, 4), 64, 0, stream>>>(x, slotE, bslot, s1p);
    k_g1  <<<1024, 256, 0, stream>>>(s1p, w1h, sc1, sh1, slotE, s2p);
    k_g2  <<<512, 256, 0, stream>>>(s2p, w2t, sc2, sh2, slotE, slotW, bslot, x, out);
}